// Round 16
// baseline (183.038 us; speedup 1.0000x reference)
//
#include <hip/hip_runtime.h>
#include <hip/hip_bf16.h>

#define B_SZ 4
#define T_SEQ 1024
#define DM 128
#define ED_ 256
#define NS 64
#define LOG2E 1.44269504088896340736f

// workspace layout (float elements). Total = 6,389,760 floats = 25.6 MB (accepted size).
// dxpT is TRANSPOSED [b][e][t] x {delta, delta*xs}; yrT is TRANSPOSED [b][e][t].
// WTiv (in_proj, float4-over-k x c) lives in the YR head: k0 -> k2, dead before k5 writes YR.
// wotv (out_proj, float4-over-k x d) lives in the XSR head: k5 extra blocks -> k6
// (MUST be built in k5, after k4b has consumed xsr -- ordering is load-bearing).
#define OFF_Z      0u         /* 524288  f32  z (residual, read by K6)            */
#define OFF_ZG     524288u    /* 1048576 f32  gate (k2 -> k6)                     */
#define OFF_XSR    1572864u   /* 1048576 f32  conv input (k2 -> k4b); head=wotv   */
#define OFF_WC     2621440u   /* 98304   f32  Wcv[k4][c] float4-over-k weight     */
#define OFF_YR     2719744u   /* 1048576 f32  scan out [b][e][t]; head hosts WTiv */
#define OFF_DPX    3768320u   /* 2097152 f32  {delta, delta*xs} [b][e][t] pairs   */
#define OFF_BC     5865472u   /* 524288  f32  {B, C} [b][t][n] pairs (k4b -> k5)  */

__device__ __forceinline__ float sigmoidf_(float x){ return 1.f/(1.f+__expf(-x)); }
__device__ __forceinline__ float exp2_(float x){ return __builtin_amdgcn_exp2f(x); }
__device__ __forceinline__ float rlane_(float v, int l){
  return __int_as_float(__builtin_amdgcn_readlane(__float_as_int(v), l));
}

// Fused DPP add: p += dpp(p) in ONE instruction. bound_ctrl:0 => invalid lanes read 0.
#define DPPR(p, ctl) asm("v_add_f32_dpp %0, %0, %0 " ctl " row_mask:0xf bank_mask:0xf bound_ctrl:0" : "+v"(p))
#define DPP6(p) do{ DPPR(p,"row_shr:1"); DPPR(p,"row_shr:2"); DPPR(p,"row_shr:4"); \
                    DPPR(p,"row_shr:8"); DPPR(p,"row_bcast:15"); DPPR(p,"row_bcast:31"); }while(0)

// K0: build WTiv: float4[(k4*512)+c] = {W[c][4k4+0..3]}.
__global__ __launch_bounds__(256) void k0_t(const float* W, float* WTi){
  int k4 = blockIdx.x >> 1;               // 0..31
  int c  = (blockIdx.x & 1)*256 + threadIdx.x;
  float4 w = *(const float4*)&W[(size_t)c*128 + 4*k4];
  ((float4*)WTi)[k4*512 + c] = w;
}

// K2f: blocks 0..511: fused [z; RMSNorm] -> LDS, then in_proj GEMM via WTiv
//      (coalesced + 4k/load). blocks 512..895: build Wcv[k4][c].
__global__ __launch_bounds__(256) void k2_fused(const float* zseq, const float* aux, const float* auxW,
                                                const float* auxb, const float* rmsw, const float* WTi,
                                                const float* xprojW, const float* dtW,
                                                float* z, float* xsr, float* zg, float* WcT){
  if (blockIdx.x >= 512){
    int r = blockIdx.x - 512; int k = threadIdx.x;
    float v;
    if (r < 256){
      v = 0.f;
      #pragma unroll
      for (int j=0;j<8;j++) v += dtW[r*8+j] * xprojW[j*256+k];
    } else {
      v = xprojW[(8 + r-256)*256 + k];
    }
    WcT[((k>>2)*384 + r)*4 + (k&3)] = v;   // scalar store into float4-over-k slot (one-off)
    return;
  }
  __shared__ float at[128][8];
  int bt0 = blockIdx.x*8; int tid = threadIdx.x;
  {
    int r = tid>>5, l = tid&31;
    int bt = bt0 + r;
    float a0 = aux[bt*3+0], a1 = aux[bt*3+1], a2 = aux[bt*3+2];
    float zv[4]; float ssq = 0.f;
    #pragma unroll
    for (int j=0;j<4;j++){
      int d = l + 32*j;
      float v = zseq[bt*DM+d] + a0*auxW[d*3+0] + a1*auxW[d*3+1] + a2*auxW[d*3+2] + auxb[d];
      zv[j] = v; ssq += v*v;
    }
    #pragma unroll
    for (int m=16;m>=1;m>>=1) ssq += __shfl_xor(ssq, m);
    float rinv = rsqrtf(ssq*(1.f/DM) + 1e-5f);
    #pragma unroll
    for (int j=0;j<4;j++){
      int d = l + 32*j;
      z[bt*DM+d] = zv[j];
      at[d][r] = zv[j]*rinv*rmsw[d];
    }
  }
  __syncthreads();
  float acc0[8], acc1[8];
  #pragma unroll
  for (int r=0;r<8;r++){ acc0[r]=0.f; acc1[r]=0.f; }
  int c0 = tid;
  const float4* WTv = (const float4*)WTi;
  for (int k4=0;k4<32;k4++){
    float4 w0 = WTv[k4*512 + c0];        // coalesced 16B/lane, 4 k's
    float4 w1 = WTv[k4*512 + c0 + 256];
    float w0a[4] = {w0.x,w0.y,w0.z,w0.w};
    float w1a[4] = {w1.x,w1.y,w1.z,w1.w};
    #pragma unroll
    for (int kk=0;kk<4;kk++){
      float a[8];
      *(float4*)&a[0] = *(const float4*)&at[4*k4+kk][0];   // broadcast b128
      *(float4*)&a[4] = *(const float4*)&at[4*k4+kk][4];
      #pragma unroll
      for (int r=0;r<8;r++){ acc0[r] = fmaf(a[r], w0a[kk], acc0[r]); acc1[r] = fmaf(a[r], w1a[kk], acc1[r]); }
    }
  }
  #pragma unroll
  for (int r=0;r<8;r++){
    int bt = bt0+r;
    xsr[bt*ED_ + c0] = acc0[r];
    zg [bt*ED_ + c0] = acc1[r];
  }
}

// K4b: conv(k=4)+bias+SiLU from xsr (LDS), then [delta_pre | B | C] = xs @ Wc
// via Wcv (coalesced + 4k/load).
__global__ __launch_bounds__(384) void k4b_xproj(const float* xsr, const float* convW, const float* convb,
                                                 const float* WcT, const float* dtb,
                                                 float* dxp, float* bcf){
  __shared__ float at[256][8];
  int bt0 = blockIdx.x*8; int tid = threadIdx.x;
  for (int i=tid;i<2048;i+=384){
    int r=i>>8,k=i&255; int bt=bt0+r; int t = bt & (T_SEQ-1);
    float4 wv = *(const float4*)(convW + k*4);
    float s = convb[k];
    if (t>=3) s += xsr[(bt-3)*ED_+k]*wv.x;
    if (t>=2) s += xsr[(bt-2)*ED_+k]*wv.y;
    if (t>=1) s += xsr[(bt-1)*ED_+k]*wv.z;
    s += xsr[bt*ED_+k]*wv.w;
    at[k][r] = s * sigmoidf_(s);
  }
  __syncthreads();
  float acc[8];
  #pragma unroll
  for (int r=0;r<8;r++) acc[r]=0.f;
  int c = tid;
  const float4* Wv = (const float4*)WcT;
  for (int k4=0;k4<64;k4++){
    float4 w = Wv[k4*384 + c];           // coalesced 16B/lane, 4 k's
    float wa[4] = {w.x,w.y,w.z,w.w};
    #pragma unroll
    for (int kk=0;kk<4;kk++){
      float a[8];
      *(float4*)&a[0] = *(const float4*)&at[4*k4+kk][0];   // broadcast
      *(float4*)&a[4] = *(const float4*)&at[4*k4+kk][4];
      #pragma unroll
      for (int r=0;r<8;r++) acc[r] = fmaf(a[r], wa[kk], acc[r]);
    }
  }
  int b4 = bt0 >> 10, tb = bt0 & (T_SEQ-1);
  if (c < 256){
    float bcv = dtb[c];
    float2* pout = (float2*)dxp + (size_t)(b4*ED_ + c)*T_SEQ + tb;
    #pragma unroll
    for (int r=0;r<8;r++){
      float xv = acc[r] + bcv;
      float dv = (xv > 20.f) ? xv : log1pf(__expf(xv));
      pout[r] = make_float2(dv, dv * at[c][r]);   // {delta, delta*xs}
    }
  } else if (c < 320){
    #pragma unroll
    for (int r=0;r<8;r++) bcf[((size_t)(bt0+r)*NS + (c-256))*2 + 0] = acc[r];
  } else {
    #pragma unroll
    for (int r=0;r<8;r++) bcf[((size_t)(bt0+r)*NS + (c-320))*2 + 1] = acc[r];
  }
}

// K5: bc-amortized scan, 4 e's PER BLOCK (R16). R14 PMC: 43.6us = issue ~25us
// (VALUBusy 57%) + stall ~19us == 492MB bc L2 stream. Halve it again: block =
// (b, 4 consecutive e's); each wave's ONE bc load feeds 4 e's. bc traffic
// ~250MB. Grid 256 scan + 16 wotv blocks, 512 thr, launch_bounds(512,4).
// Reduce tile stays [16][2][66] (67.6KB): e-pairs processed in two sub-batches,
// pair-1 pp's parked in 32 unrolled registers. lcar/lapr OVERLAY red's head
// (union) -- guarded by a 2nd __syncthreads after the combine. Phase-2 bc is
// single-buffered to keep VGPR ~90 << cap 128 (no R2-style collapse).
__global__ __launch_bounds__(512,4) void k5_scan(const float* dxpf, const float* bcf,
                                                  const float* Alog, float* yrT,
                                                  const float* outW, float* wot){
  if (blockIdx.x >= 256){
    int idx = (blockIdx.x - 256)*512 + threadIdx.x;   // 0..8191
    int k4 = idx >> 7;                                // 0..63
    int d  = idx & 127;
    float4 v = *(const float4*)&outW[(size_t)d*256 + 4*k4];
    ((float4*)wot)[k4*128 + d] = v;
    return;
  }
  __shared__ float red[8][16][2][66];    // 67584 B; head doubles as lcar/lapr (union)
  float* lcarF = (float*)red;            // [7][4][64] carries
  float* laprF = lcarF + 7*4*64;         // [7][4][64] decays
  int i  = blockIdx.x;
  int tid = threadIdx.x;
  int wv = tid >> 6;             // wave 0..7 == chunk index
  int n  = tid & 63;             // state index (lane)
  int x = i & 7;                 // XCD
  int r = i >> 3;                // 0..31
  int b = r & 3;
  int gg = r >> 2;               // 0..7
  int e0 = x*32 + gg*4;
  const int CH = T_SEQ/8;        // 128
  int t0 = wv*CH;
  float A2[4];
  #pragma unroll
  for (int e=0;e<4;e++) A2[e] = -__expf(Alog[(e0+e)*NS+n]) * LOG2E;
  const float2* pbc = (const float2*)bcf + (size_t)(b*T_SEQ + t0)*NS + n;   // lane=n
  const float2* pd0 = (const float2*)dxpf + (size_t)(b*ED_ + e0)*T_SEQ + t0; // lane=t; e stride = T_SEQ

  // ---- phase 1: carry-only scan (waves 0..6; wave 7's carry unused)
  if (wv < 7){
    float h[4] = {0.f,0.f,0.f,0.f}, Ss[4] = {0.f,0.f,0.f,0.f};
    for (int sb=0; sb<CH; sb+=64){
      float2 dxc[4];
      #pragma unroll
      for (int e=0;e<4;e++) dxc[e] = pd0[(size_t)e*T_SEQ + sb + n];
      #pragma unroll
      for (int e=0;e<4;e++){ float sv = dxc[e].x; DPP6(sv); Ss[e] += rlane_(sv, 63); }
      float bA[8], bB[8];
      #pragma unroll
      for (int j=0;j<8;j++) bA[j] = pbc[(sb+j)*NS].x;
      #pragma unroll
      for (int bb=0; bb<64; bb+=16){
        #pragma unroll
        for (int j=0;j<8;j++) bB[j] = pbc[(sb+bb+8+j)*NS].x;
        #pragma unroll
        for (int j=0;j<8;j++){
          #pragma unroll
          for (int e=0;e<4;e++){
            float sd = rlane_(dxc[e].x, bb+j), su = rlane_(dxc[e].y, bb+j);
            h[e] = fmaf(exp2_(sd*A2[e]), h[e], su*bA[j]);
          }
        }
        if (bb+16 < 64){
          #pragma unroll
          for (int j=0;j<8;j++) bA[j] = pbc[(sb+bb+16+j)*NS].x;
        }
        #pragma unroll
        for (int j=0;j<8;j++){
          #pragma unroll
          for (int e=0;e<4;e++){
            float sd = rlane_(dxc[e].x, bb+8+j), su = rlane_(dxc[e].y, bb+8+j);
            h[e] = fmaf(exp2_(sd*A2[e]), h[e], su*bB[j]);
          }
        }
      }
    }
    #pragma unroll
    for (int e=0;e<4;e++){
      lcarF[(wv*4+e)*64+n] = h[e];
      laprF[(wv*4+e)*64+n] = exp2_(A2[e]*Ss[e]);
    }
  }
  __syncthreads();

  // ---- combine: h_in for this wave's chunk (all 4 e's)
  float h[4] = {0.f,0.f,0.f,0.f};
  #pragma unroll
  for (int q=0;q<7;q++) if (wv > q){
    #pragma unroll
    for (int e=0;e<4;e++)
      h[e] = fmaf(laprF[(q*4+e)*64+n], h[e], lcarF[(q*4+e)*64+n]);
  }
  __syncthreads();   // union safety: all lcar/lapr reads done before red writes

  // ---- phase 2: full output scan; one bc load feeds 4 e's
  {
    int ri = n & 31, hs = n >> 5;
    int eh = ri >> 4, tr = ri & 15;
    const float2* rp = (const float2*)&red[wv][tr][eh][hs*32];
    float* py0e = yrT + (size_t)(b*ED_ + e0 + eh    )*T_SEQ + t0;  // pair-0 row
    float* py1e = yrT + (size_t)(b*ED_ + e0 + 2 + eh)*T_SEQ + t0;  // pair-1 row
    for (int sb=0; sb<CH; sb+=64){
      float2 dxc[4];
      #pragma unroll
      for (int e=0;e<4;e++) dxc[e] = pd0[(size_t)e*T_SEQ + sb + n];
      for (int bb=0; bb<64; bb+=16){
        float pp2[16], pp3[16];
        float2 cA[8];
        #pragma unroll
        for (int j=0;j<8;j++) cA[j] = pbc[(sb+bb+j)*NS];
        #pragma unroll
        for (int j=0;j<8;j++){
          float sd0 = rlane_(dxc[0].x, bb+j), su0 = rlane_(dxc[0].y, bb+j);
          h[0] = fmaf(exp2_(sd0*A2[0]), h[0], su0*cA[j].x);
          red[wv][j][0][n] = h[0]*cA[j].y;
          float sd1 = rlane_(dxc[1].x, bb+j), su1 = rlane_(dxc[1].y, bb+j);
          h[1] = fmaf(exp2_(sd1*A2[1]), h[1], su1*cA[j].x);
          red[wv][j][1][n] = h[1]*cA[j].y;
          float sd2 = rlane_(dxc[2].x, bb+j), su2 = rlane_(dxc[2].y, bb+j);
          h[2] = fmaf(exp2_(sd2*A2[2]), h[2], su2*cA[j].x);
          pp2[j] = h[2]*cA[j].y;
          float sd3 = rlane_(dxc[3].x, bb+j), su3 = rlane_(dxc[3].y, bb+j);
          h[3] = fmaf(exp2_(sd3*A2[3]), h[3], su3*cA[j].x);
          pp3[j] = h[3]*cA[j].y;
        }
        #pragma unroll
        for (int j=0;j<8;j++) cA[j] = pbc[(sb+bb+8+j)*NS];
        #pragma unroll
        for (int j=0;j<8;j++){
          float sd0 = rlane_(dxc[0].x, bb+8+j), su0 = rlane_(dxc[0].y, bb+8+j);
          h[0] = fmaf(exp2_(sd0*A2[0]), h[0], su0*cA[j].x);
          red[wv][8+j][0][n] = h[0]*cA[j].y;
          float sd1 = rlane_(dxc[1].x, bb+8+j), su1 = rlane_(dxc[1].y, bb+8+j);
          h[1] = fmaf(exp2_(sd1*A2[1]), h[1], su1*cA[j].x);
          red[wv][8+j][1][n] = h[1]*cA[j].y;
          float sd2 = rlane_(dxc[2].x, bb+8+j), su2 = rlane_(dxc[2].y, bb+8+j);
          h[2] = fmaf(exp2_(sd2*A2[2]), h[2], su2*cA[j].x);
          pp2[8+j] = h[2]*cA[j].y;
          float sd3 = rlane_(dxc[3].x, bb+8+j), su3 = rlane_(dxc[3].y, bb+8+j);
          h[3] = fmaf(exp2_(sd3*A2[3]), h[3], su3*cA[j].x);
          pp3[8+j] = h[3]*cA[j].y;
        }
        // reduce pair 0 (e0+0, e0+1) -- same-wave DS ops are in-order
        {
          float s = 0.f;
          #pragma unroll
          for (int jj=0;jj<16;jj++){ float2 v = rp[jj]; s += v.x + v.y; }
          s += __shfl_xor(s, 32);
          if (n < 32) py0e[sb + bb + tr] = s;
        }
        // stage pair 1 (e0+2, e0+3) into red, then reduce
        #pragma unroll
        for (int j=0;j<16;j++){
          red[wv][j][0][n] = pp2[j];
          red[wv][j][1][n] = pp3[j];
        }
        {
          float s = 0.f;
          #pragma unroll
          for (int jj=0;jj<16;jj++){ float2 v = rp[jj]; s += v.x + v.y; }
          s += __shfl_xor(s, 32);
          if (n < 32) py1e[sb + bb + tr] = s;
        }
      }
    }
  }
}

// K6: stage yrT (e-major) + xs = u/delta from dxpT via LDS; combine with gate;
// then out = LayerNorm(y @ out_proj_W.T + 2*z)*ln_w + ln_b.
// Weight reads via wotv: coalesced over d AND 4 k's per float4 load.
__global__ __launch_bounds__(256) void k6_out(const float* yrT, const float* dxpf, const float* zg,
                                               const float* Dp, const float* wot, const float* z,
                                               const float* lnw, const float* lnb, float* out){
  __shared__ float yt[256][8];
  __shared__ float xst[256][8];
  __shared__ float psum[4][4], psq[4][4];
  int bt0 = blockIdx.x*8; int tid = threadIdx.x;
  int b4 = bt0 >> 10, tb = bt0 & (T_SEQ-1);
  int el = tid>>3, tl = tid&7;
  #pragma unroll
  for (int gg=0; gg<8; gg++){
    int ee = el + gg*32;
    size_t base = (size_t)(b4*ED_ + ee)*T_SEQ + tb + tl;
    float2 du = ((const float2*)dxpf)[base];
    yt[ee][tl]  = yrT[base];
    xst[ee][tl] = du.y / du.x;        // xs = (delta*xs)/delta; delta >= softplus(-4) ~ 0.018
  }
  __syncthreads();
  for (int i=tid;i<2048;i+=256){
    int rr=i>>8, k=i&255; int bt=bt0+rr;
    float zgv = zg[bt*ED_ + k];
    float yv  = yt[k][rr] + Dp[k]*xst[k][rr];
    yt[k][rr] = yv * zgv * sigmoidf_(zgv);
  }
  __syncthreads();
  int d = tid & 127, gdx = tid>>7;
  float acc[4] = {0.f,0.f,0.f,0.f};
  const float4* Wv = (const float4*)wot;
  for (int k4=0;k4<64;k4++){
    float4 w = Wv[k4*128 + d];           // coalesced 16B/lane, 4 k's
    int k = k4*4;
    float4 q0 = *(const float4*)&yt[k+0][gdx*4];   // broadcast
    float4 q1 = *(const float4*)&yt[k+1][gdx*4];
    float4 q2 = *(const float4*)&yt[k+2][gdx*4];
    float4 q3 = *(const float4*)&yt[k+3][gdx*4];
    acc[0] = fmaf(q0.x,w.x,acc[0]); acc[1] = fmaf(q0.y,w.x,acc[1]);
    acc[2] = fmaf(q0.z,w.x,acc[2]); acc[3] = fmaf(q0.w,w.x,acc[3]);
    acc[0] = fmaf(q1.x,w.y,acc[0]); acc[1] = fmaf(q1.y,w.y,acc[1]);
    acc[2] = fmaf(q1.z,w.y,acc[2]); acc[3] = fmaf(q1.w,w.y,acc[3]);
    acc[0] = fmaf(q2.x,w.z,acc[0]); acc[1] = fmaf(q2.y,w.z,acc[1]);
    acc[2] = fmaf(q2.z,w.z,acc[2]); acc[3] = fmaf(q2.w,w.z,acc[3]);
    acc[0] = fmaf(q3.x,w.w,acc[0]); acc[1] = fmaf(q3.y,w.w,acc[1]);
    acc[2] = fmaf(q3.z,w.w,acc[2]); acc[3] = fmaf(q3.w,w.w,acc[3]);
  }
  float val[4];
  #pragma unroll
  for (int j=0;j<4;j++){
    int bt = bt0 + gdx*4 + j;
    val[j] = acc[j] + 2.f*z[bt*DM + d];
  }
  int w_id = tid>>6;
  #pragma unroll
  for (int j=0;j<4;j++){
    float s = val[j], q = val[j]*val[j];
    #pragma unroll
    for (int off=32; off>=1; off>>=1){ s += __shfl_down(s, off); q += __shfl_down(q, off); }
    if ((tid&63)==0){ psum[w_id][j]=s; psq[w_id][j]=q; }
  }
  __syncthreads();
  float lw = lnw[d], lb = lnb[d];
  #pragma unroll
  for (int j=0;j<4;j++){
    int bt = bt0 + gdx*4 + j;
    float sum = psum[gdx*2][j] + psum[gdx*2+1][j];
    float sq  = psq [gdx*2][j] + psq [gdx*2+1][j];
    float mu  = sum*(1.f/DM);
    float var = sq*(1.f/DM) - mu*mu;
    float inv = rsqrtf(var + 1e-5f);
    out[bt*DM + d] = (val[j]-mu)*inv*lw + lb;
  }
}

extern "C" void kernel_launch(void* const* d_in, const int* in_sizes, int n_in,
                              void* d_out, int out_size, void* d_ws, size_t ws_size,
                              hipStream_t stream){
  const float* zseq = (const float*)d_in[0];
  const float* aux  = (const float*)d_in[1];
  const float* auxW = (const float*)d_in[2];
  const float* auxb = (const float*)d_in[3];
  const float* lnw  = (const float*)d_in[4];
  const float* lnb  = (const float*)d_in[5];
  const float* rmsw = (const float*)d_in[6];
  const float* inW  = (const float*)d_in[7];
  const float* convW= (const float*)d_in[8];
  const float* convb= (const float*)d_in[9];
  const float* xpW  = (const float*)d_in[10];
  const float* dtW  = (const float*)d_in[11];
  const float* dtb  = (const float*)d_in[12];
  const float* Alog = (const float*)d_in[13];
  const float* Dp   = (const float*)d_in[14];
  const float* outW = (const float*)d_in[15];
  float* out = (float*)d_out;
  float* ws = (float*)d_ws;

  float* z   = ws+OFF_Z;
  float* zg  = ws+OFF_ZG;
  float* xsr = ws+OFF_XSR;
  float* wot = ws+OFF_XSR;   // wotv hosted in XSR head; xsr dead after k4b
  float* WcT = ws+OFF_WC;
  float* yr  = ws+OFF_YR;
  float* wti = ws+OFF_YR;    // WTiv hosted in YR head; dead before k5 writes yr
  float* dxp = ws+OFF_DPX;
  float* bcp = ws+OFF_BC;

  k0_t     <<<64,256,0,stream>>>(inW, wti);
  k2_fused <<<896,256,0,stream>>>(zseq,aux,auxW,auxb,rmsw,wti,xpW,dtW,z,xsr,zg,WcT);
  k4b_xproj<<<512,384,0,stream>>>(xsr,convW,convb,WcT,dtb,dxp,bcp);
  k5_scan  <<<272,512,0,stream>>>(dxp,bcp,Alog,yr,outW,wot);
  k6_out   <<<512,256,0,stream>>>(yr,dxp,zg,Dp,wot,z,lnw,lnb,out);
}

// Round 17
// 181.479 us; speedup vs baseline: 1.0086x; 1.0086x over previous
//
#include <hip/hip_runtime.h>
#include <hip/hip_bf16.h>

#define B_SZ 4
#define T_SEQ 1024
#define DM 128
#define ED_ 256
#define NS 64
#define LOG2E 1.44269504088896340736f

// workspace layout (float elements). Total = 6,389,760 floats = 25.6 MB (accepted size).
// dxpT is TRANSPOSED [b][e][t] x {delta, delta*xs}; yrT is TRANSPOSED [b][e][t].
// WTiv (in_proj, float4-over-k x c) lives in the YR head: k0 -> k2, dead before k5 writes YR.
// wotv (out_proj, float4-over-k x d) lives in the XSR head: k5 extra blocks -> k6.
#define OFF_Z      0u         /* 524288  f32  z (residual, read by K6)            */
#define OFF_ZG     524288u    /* 1048576 f32  gate (k2 -> k6)                     */
#define OFF_XSR    1572864u   /* 1048576 f32  conv input (k2 -> k4b); head=wotv   */
#define OFF_WC     2621440u   /* 98304   f32  Wcv[k4][c] float4-over-k weight     */
#define OFF_YR     2719744u   /* 1048576 f32  scan out [b][e][t]; head hosts WTiv */
#define OFF_DPX    3768320u   /* 2097152 f32  {delta, delta*xs} [b][e][t] pairs   */
#define OFF_BC     5865472u   /* 524288  f32  {B, C} [b][t][n] pairs (k4b -> k5)  */

__device__ __forceinline__ float sigmoidf_(float x){ return 1.f/(1.f+__expf(-x)); }
__device__ __forceinline__ float exp2_(float x){ return __builtin_amdgcn_exp2f(x); }
__device__ __forceinline__ float rlane_(float v, int l){
  return __int_as_float(__builtin_amdgcn_readlane(__float_as_int(v), l));
}

// Fused DPP add: p += dpp(p) in ONE instruction. bound_ctrl:0 => invalid lanes read 0.
#define DPPR(p, ctl) asm("v_add_f32_dpp %0, %0, %0 " ctl " row_mask:0xf bank_mask:0xf bound_ctrl:0" : "+v"(p))
#define DPP6(p) do{ DPPR(p,"row_shr:1"); DPPR(p,"row_shr:2"); DPPR(p,"row_shr:4"); \
                    DPPR(p,"row_shr:8"); DPPR(p,"row_bcast:15"); DPPR(p,"row_bcast:31"); }while(0)

// K0: build WTiv: float4[(k4*512)+c] = {W[c][4k4+0..3]}.
__global__ __launch_bounds__(256) void k0_t(const float* W, float* WTi){
  int k4 = blockIdx.x >> 1;               // 0..31
  int c  = (blockIdx.x & 1)*256 + threadIdx.x;
  float4 w = *(const float4*)&W[(size_t)c*128 + 4*k4];
  ((float4*)WTi)[k4*512 + c] = w;
}

// K2f: blocks 0..511: fused [z; RMSNorm] -> LDS, then in_proj GEMM via WTiv
//      (coalesced + 4k/load + 1-AHEAD PREFETCH: R17 theory is that the GEMM trio
//      is latency-bound on weight loads consumed immediately; a 1-deep float4
//      rotation (8 VGPR) hides ~300cyc L2 latency under the 150cyc of fma).
//      blocks 512..895: build Wcv[k4][c].
__global__ __launch_bounds__(256) void k2_fused(const float* zseq, const float* aux, const float* auxW,
                                                const float* auxb, const float* rmsw, const float* WTi,
                                                const float* xprojW, const float* dtW,
                                                float* z, float* xsr, float* zg, float* WcT){
  if (blockIdx.x >= 512){
    int r = blockIdx.x - 512; int k = threadIdx.x;
    float v;
    if (r < 256){
      v = 0.f;
      #pragma unroll
      for (int j=0;j<8;j++) v += dtW[r*8+j] * xprojW[j*256+k];
    } else {
      v = xprojW[(8 + r-256)*256 + k];
    }
    WcT[((k>>2)*384 + r)*4 + (k&3)] = v;   // scalar store into float4-over-k slot (one-off)
    return;
  }
  __shared__ float at[128][8];
  int bt0 = blockIdx.x*8; int tid = threadIdx.x;
  {
    int r = tid>>5, l = tid&31;
    int bt = bt0 + r;
    float a0 = aux[bt*3+0], a1 = aux[bt*3+1], a2 = aux[bt*3+2];
    float zv[4]; float ssq = 0.f;
    #pragma unroll
    for (int j=0;j<4;j++){
      int d = l + 32*j;
      float v = zseq[bt*DM+d] + a0*auxW[d*3+0] + a1*auxW[d*3+1] + a2*auxW[d*3+2] + auxb[d];
      zv[j] = v; ssq += v*v;
    }
    #pragma unroll
    for (int m=16;m>=1;m>>=1) ssq += __shfl_xor(ssq, m);
    float rinv = rsqrtf(ssq*(1.f/DM) + 1e-5f);
    #pragma unroll
    for (int j=0;j<4;j++){
      int d = l + 32*j;
      z[bt*DM+d] = zv[j];
      at[d][r] = zv[j]*rinv*rmsw[d];
    }
  }
  __syncthreads();
  float acc0[8], acc1[8];
  #pragma unroll
  for (int r=0;r<8;r++){ acc0[r]=0.f; acc1[r]=0.f; }
  int c0 = tid;
  const float4* WTv = (const float4*)WTi;
  float4 w0 = WTv[c0];
  float4 w1 = WTv[c0 + 256];
  for (int k4=0;k4<32;k4++){
    int kn = (k4+1) & 31;                   // wraps on last iter: harmless L2-hit load
    float4 nw0 = WTv[kn*512 + c0];
    float4 nw1 = WTv[kn*512 + c0 + 256];
    float w0a[4] = {w0.x,w0.y,w0.z,w0.w};
    float w1a[4] = {w1.x,w1.y,w1.z,w1.w};
    #pragma unroll
    for (int kk=0;kk<4;kk++){
      float a[8];
      *(float4*)&a[0] = *(const float4*)&at[4*k4+kk][0];   // broadcast b128
      *(float4*)&a[4] = *(const float4*)&at[4*k4+kk][4];
      #pragma unroll
      for (int r=0;r<8;r++){ acc0[r] = fmaf(a[r], w0a[kk], acc0[r]); acc1[r] = fmaf(a[r], w1a[kk], acc1[r]); }
    }
    w0 = nw0; w1 = nw1;
  }
  #pragma unroll
  for (int r=0;r<8;r++){
    int bt = bt0+r;
    xsr[bt*ED_ + c0] = acc0[r];
    zg [bt*ED_ + c0] = acc1[r];
  }
}

// K4b: conv(k=4)+bias+SiLU from xsr (LDS), then [delta_pre | B | C] = xs @ Wc
// via Wcv (coalesced + 4k/load + 1-ahead prefetch).
__global__ __launch_bounds__(384) void k4b_xproj(const float* xsr, const float* convW, const float* convb,
                                                 const float* WcT, const float* dtb,
                                                 float* dxp, float* bcf){
  __shared__ float at[256][8];
  int bt0 = blockIdx.x*8; int tid = threadIdx.x;
  for (int i=tid;i<2048;i+=384){
    int r=i>>8,k=i&255; int bt=bt0+r; int t = bt & (T_SEQ-1);
    float4 wv = *(const float4*)(convW + k*4);
    float s = convb[k];
    if (t>=3) s += xsr[(bt-3)*ED_+k]*wv.x;
    if (t>=2) s += xsr[(bt-2)*ED_+k]*wv.y;
    if (t>=1) s += xsr[(bt-1)*ED_+k]*wv.z;
    s += xsr[bt*ED_+k]*wv.w;
    at[k][r] = s * sigmoidf_(s);
  }
  __syncthreads();
  float acc[8];
  #pragma unroll
  for (int r=0;r<8;r++) acc[r]=0.f;
  int c = tid;
  const float4* Wv = (const float4*)WcT;
  float4 w = Wv[c];
  for (int k4=0;k4<64;k4++){
    int kn = (k4+1) & 63;                   // wraps on last iter
    float4 nw = Wv[kn*384 + c];
    float wa[4] = {w.x,w.y,w.z,w.w};
    #pragma unroll
    for (int kk=0;kk<4;kk++){
      float a[8];
      *(float4*)&a[0] = *(const float4*)&at[4*k4+kk][0];   // broadcast
      *(float4*)&a[4] = *(const float4*)&at[4*k4+kk][4];
      #pragma unroll
      for (int r=0;r<8;r++) acc[r] = fmaf(a[r], wa[kk], acc[r]);
    }
    w = nw;
  }
  int b4 = bt0 >> 10, tb = bt0 & (T_SEQ-1);
  if (c < 256){
    float bcv = dtb[c];
    float2* pout = (float2*)dxp + (size_t)(b4*ED_ + c)*T_SEQ + tb;
    #pragma unroll
    for (int r=0;r<8;r++){
      float xv = acc[r] + bcv;
      float dv = (xv > 20.f) ? xv : log1pf(__expf(xv));
      pout[r] = make_float2(dv, dv * at[c][r]);   // {delta, delta*xs}
    }
  } else if (c < 320){
    #pragma unroll
    for (int r=0;r<8;r++) bcf[((size_t)(bt0+r)*NS + (c-256))*2 + 0] = acc[r];
  } else {
    #pragma unroll
    for (int r=0;r<8;r++) bcf[((size_t)(bt0+r)*NS + (c-320))*2 + 1] = acc[r];
  }
}

// K5: bc-amortized chunked scan (R15/R14 config, measured best 43.6-44.4us):
// block = (b, 2 e's), 8 waves x 8 chunks of 128 t; one bc float2 load feeds
// 2 e's. Grid 512 scan blocks + 16 wotv-builder blocks. launch_bounds(512,4).
// R16's 4-e variant regressed (occupancy 17%, FETCH up) -- reverted.
__global__ __launch_bounds__(512,4) void k5_scan(const float* dxpf, const float* bcf,
                                                  const float* Alog, float* yrT,
                                                  const float* outW, float* wot){
  if (blockIdx.x >= 512){
    int idx = (blockIdx.x - 512)*512 + threadIdx.x;   // 0..8191
    int k4 = idx >> 7;                                // 0..63
    int d  = idx & 127;
    float4 v = *(const float4*)&outW[(size_t)d*256 + 4*k4];  // 4 k's, aligned
    ((float4*)wot)[k4*128 + d] = v;                   // coalesced over d
    return;
  }
  __shared__ float lcar[7][2][64], lapr[7][2][64];
  __shared__ float red[8][16][2][66];
  int i  = blockIdx.x;
  int tid = threadIdx.x;
  int wv = tid >> 6;             // wave 0..7 == chunk index
  int n  = tid & 63;             // state index (lane)
  int x = i & 7;                 // XCD
  int r = i >> 3;                // 0..63
  int b = r & 3;
  int g = r >> 2;                // 0..15
  int eA = x*32 + g*2;
  int eB = eA + 1;
  const int CH = T_SEQ/8;        // 128
  int t0 = wv*CH;
  float A2A = -__expf(Alog[eA*NS+n]) * LOG2E;
  float A2B = -__expf(Alog[eB*NS+n]) * LOG2E;
  const float2* pdA = (const float2*)dxpf + (size_t)(b*ED_ + eA)*T_SEQ + t0;  // lane=t
  const float2* pdB = (const float2*)dxpf + (size_t)(b*ED_ + eB)*T_SEQ + t0;
  const float2* pbc = (const float2*)bcf  + (size_t)(b*T_SEQ + t0)*NS + n;    // lane=n
  float* pyA = yrT + (size_t)(b*ED_ + eA)*T_SEQ + t0;
  float* pyB = yrT + (size_t)(b*ED_ + eB)*T_SEQ + t0;

  // ---- phase 1: carry-only scan (waves 0..6; wave 7's carry unused)
  if (wv < 7){
    float hA=0.f, hB=0.f, SsA=0.f, SsB=0.f;
    float2 dxcA = pdA[n], dxcB = pdB[n];
    for (int sb=0; sb<CH; sb+=64){
      float2 dxnA = dxcA, dxnB = dxcB;
      if (sb+64 < CH){ dxnA = pdA[sb+64+n]; dxnB = pdB[sb+64+n]; }
      float svA = dxcA.x; DPP6(svA); SsA += rlane_(svA, 63);
      float svB = dxcB.x; DPP6(svB); SsB += rlane_(svB, 63);
      float bA[8], bBv[8];
      #pragma unroll
      for (int j=0;j<8;j++) bA[j] = pbc[(sb+j)*NS].x;
      #pragma unroll
      for (int bb=0; bb<64; bb+=16){
        #pragma unroll
        for (int j=0;j<8;j++) bBv[j] = pbc[(sb+bb+8+j)*NS].x;
        #pragma unroll
        for (int j=0;j<8;j++){
          float sdA = rlane_(dxcA.x, bb+j), suA = rlane_(dxcA.y, bb+j);
          hA = fmaf(exp2_(sdA*A2A), hA, suA*bA[j]);
          float sdB = rlane_(dxcB.x, bb+j), suB = rlane_(dxcB.y, bb+j);
          hB = fmaf(exp2_(sdB*A2B), hB, suB*bA[j]);
        }
        if (bb+16 < 64){
          #pragma unroll
          for (int j=0;j<8;j++) bA[j] = pbc[(sb+bb+16+j)*NS].x;
        }
        #pragma unroll
        for (int j=0;j<8;j++){
          float sdA = rlane_(dxcA.x, bb+8+j), suA = rlane_(dxcA.y, bb+8+j);
          hA = fmaf(exp2_(sdA*A2A), hA, suA*bBv[j]);
          float sdB = rlane_(dxcB.x, bb+8+j), suB = rlane_(dxcB.y, bb+8+j);
          hB = fmaf(exp2_(sdB*A2B), hB, suB*bBv[j]);
        }
      }
      dxcA = dxnA; dxcB = dxnB;
    }
    lcar[wv][0][n] = hA;  lapr[wv][0][n] = exp2_(A2A*SsA);
    lcar[wv][1][n] = hB;  lapr[wv][1][n] = exp2_(A2B*SsB);
  }
  __syncthreads();

  // ---- combine: h_in for this wave's chunk (both e's)
  float hA = 0.f, hB = 0.f;
  #pragma unroll
  for (int q=0;q<7;q++) if (wv > q){
    hA = fmaf(lapr[q][0][n], hA, lcar[q][0][n]);
    hB = fmaf(lapr[q][1][n], hB, lcar[q][1][n]);
  }

  // ---- phase 2: full output scan, shared bc load feeds both e's
  {
    float2 dxcA = pdA[n], dxcB = pdB[n];
    int ri = n & 31, hs = n >> 5;
    int eh = ri >> 4, tr = ri & 15;
    const float2* rp = (const float2*)&red[wv][tr][eh][hs*32];
    float* pyE = eh ? pyB : pyA;
    for (int sb=0; sb<CH; sb+=64){
      float2 dxnA = dxcA, dxnB = dxcB;
      if (sb+64 < CH){ dxnA = pdA[sb+64+n]; dxnB = pdB[sb+64+n]; }
      float2 cA[8], cB[8];
      #pragma unroll
      for (int j=0;j<8;j++) cA[j] = pbc[(sb+j)*NS];
      #pragma unroll
      for (int bb=0; bb<64; bb+=16){
        #pragma unroll
        for (int j=0;j<8;j++) cB[j] = pbc[(sb+bb+8+j)*NS];
        #pragma unroll
        for (int j=0;j<8;j++){
          float sdA = rlane_(dxcA.x, bb+j), suA = rlane_(dxcA.y, bb+j);
          hA = fmaf(exp2_(sdA*A2A), hA, suA*cA[j].x);
          red[wv][j][0][n] = hA*cA[j].y;
          float sdB = rlane_(dxcB.x, bb+j), suB = rlane_(dxcB.y, bb+j);
          hB = fmaf(exp2_(sdB*A2B), hB, suB*cA[j].x);
          red[wv][j][1][n] = hB*cA[j].y;
        }
        if (bb+16 < 64){
          #pragma unroll
          for (int j=0;j<8;j++) cA[j] = pbc[(sb+bb+16+j)*NS];
        }
        #pragma unroll
        for (int j=0;j<8;j++){
          float sdA = rlane_(dxcA.x, bb+8+j), suA = rlane_(dxcA.y, bb+8+j);
          hA = fmaf(exp2_(sdA*A2A), hA, suA*cB[j].x);
          red[wv][8+j][0][n] = hA*cB[j].y;
          float sdB = rlane_(dxcB.x, bb+8+j), suB = rlane_(dxcB.y, bb+8+j);
          hB = fmaf(exp2_(sdB*A2B), hB, suB*cB[j].x);
          red[wv][8+j][1][n] = hB*cB[j].y;
        }
        // transpose-reduce the 16t x 2e tile (same-wave DS ops are in-order)
        float s = 0.f;
        #pragma unroll
        for (int jj=0;jj<16;jj++){ float2 v = rp[jj]; s += v.x + v.y; }
        s += __shfl_xor(s, 32);
        if (n < 32) pyE[sb + bb + tr] = s;
      }
      dxcA = dxnA; dxcB = dxnB;
    }
  }
}

// K6: stage yrT (e-major) + xs = u/delta from dxpT via LDS; combine with gate;
// then out = LayerNorm(y @ out_proj_W.T + 2*z)*ln_w + ln_b.
// Weight reads via wotv: coalesced over d, 4 k's per float4 load, 1-ahead prefetch.
__global__ __launch_bounds__(256) void k6_out(const float* yrT, const float* dxpf, const float* zg,
                                               const float* Dp, const float* wot, const float* z,
                                               const float* lnw, const float* lnb, float* out){
  __shared__ float yt[256][8];
  __shared__ float xst[256][8];
  __shared__ float psum[4][4], psq[4][4];
  int bt0 = blockIdx.x*8; int tid = threadIdx.x;
  int b4 = bt0 >> 10, tb = bt0 & (T_SEQ-1);
  int el = tid>>3, tl = tid&7;
  #pragma unroll
  for (int gg=0; gg<8; gg++){
    int ee = el + gg*32;
    size_t base = (size_t)(b4*ED_ + ee)*T_SEQ + tb + tl;
    float2 du = ((const float2*)dxpf)[base];
    yt[ee][tl]  = yrT[base];
    xst[ee][tl] = du.y / du.x;        // xs = (delta*xs)/delta; delta >= softplus(-4) ~ 0.018
  }
  __syncthreads();
  for (int i=tid;i<2048;i+=256){
    int rr=i>>8, k=i&255; int bt=bt0+rr;
    float zgv = zg[bt*ED_ + k];
    float yv  = yt[k][rr] + Dp[k]*xst[k][rr];
    yt[k][rr] = yv * zgv * sigmoidf_(zgv);
  }
  __syncthreads();
  int d = tid & 127, gdx = tid>>7;
  float acc[4] = {0.f,0.f,0.f,0.f};
  const float4* Wv = (const float4*)wot;
  float4 w = Wv[d];
  for (int k4=0;k4<64;k4++){
    int kn = (k4+1) & 63;                   // wraps on last iter
    float4 nw = Wv[kn*128 + d];
    int k = k4*4;
    float4 q0 = *(const float4*)&yt[k+0][gdx*4];   // broadcast
    float4 q1 = *(const float4*)&yt[k+1][gdx*4];
    float4 q2 = *(const float4*)&yt[k+2][gdx*4];
    float4 q3 = *(const float4*)&yt[k+3][gdx*4];
    acc[0] = fmaf(q0.x,w.x,acc[0]); acc[1] = fmaf(q0.y,w.x,acc[1]);
    acc[2] = fmaf(q0.z,w.x,acc[2]); acc[3] = fmaf(q0.w,w.x,acc[3]);
    acc[0] = fmaf(q1.x,w.y,acc[0]); acc[1] = fmaf(q1.y,w.y,acc[1]);
    acc[2] = fmaf(q1.z,w.y,acc[2]); acc[3] = fmaf(q1.w,w.y,acc[3]);
    acc[0] = fmaf(q2.x,w.z,acc[0]); acc[1] = fmaf(q2.y,w.z,acc[1]);
    acc[2] = fmaf(q2.z,w.z,acc[2]); acc[3] = fmaf(q2.w,w.z,acc[3]);
    acc[0] = fmaf(q3.x,w.w,acc[0]); acc[1] = fmaf(q3.y,w.w,acc[1]);
    acc[2] = fmaf(q3.z,w.w,acc[2]); acc[3] = fmaf(q3.w,w.w,acc[3]);
    w = nw;
  }
  float val[4];
  #pragma unroll
  for (int j=0;j<4;j++){
    int bt = bt0 + gdx*4 + j;
    val[j] = acc[j] + 2.f*z[bt*DM + d];
  }
  int w_id = tid>>6;
  #pragma unroll
  for (int j=0;j<4;j++){
    float s = val[j], q = val[j]*val[j];
    #pragma unroll
    for (int off=32; off>=1; off>>=1){ s += __shfl_down(s, off); q += __shfl_down(q, off); }
    if ((tid&63)==0){ psum[w_id][j]=s; psq[w_id][j]=q; }
  }
  __syncthreads();
  float lw = lnw[d], lb = lnb[d];
  #pragma unroll
  for (int j=0;j<4;j++){
    int bt = bt0 + gdx*4 + j;
    float sum = psum[gdx*2][j] + psum[gdx*2+1][j];
    float sq  = psq [gdx*2][j] + psq [gdx*2+1][j];
    float mu  = sum*(1.f/DM);
    float var = sq*(1.f/DM) - mu*mu;
    float inv = rsqrtf(var + 1e-5f);
    out[bt*DM + d] = (val[j]-mu)*inv*lw + lb;
  }
}

extern "C" void kernel_launch(void* const* d_in, const int* in_sizes, int n_in,
                              void* d_out, int out_size, void* d_ws, size_t ws_size,
                              hipStream_t stream){
  const float* zseq = (const float*)d_in[0];
  const float* aux  = (const float*)d_in[1];
  const float* auxW = (const float*)d_in[2];
  const float* auxb = (const float*)d_in[3];
  const float* lnw  = (const float*)d_in[4];
  const float* lnb  = (const float*)d_in[5];
  const float* rmsw = (const float*)d_in[6];
  const float* inW  = (const float*)d_in[7];
  const float* convW= (const float*)d_in[8];
  const float* convb= (const float*)d_in[9];
  const float* xpW  = (const float*)d_in[10];
  const float* dtW  = (const float*)d_in[11];
  const float* dtb  = (const float*)d_in[12];
  const float* Alog = (const float*)d_in[13];
  const float* Dp   = (const float*)d_in[14];
  const float* outW = (const float*)d_in[15];
  float* out = (float*)d_out;
  float* ws = (float*)d_ws;

  float* z   = ws+OFF_Z;
  float* zg  = ws+OFF_ZG;
  float* xsr = ws+OFF_XSR;
  float* wot = ws+OFF_XSR;   // wotv hosted in XSR head; xsr dead after k4b
  float* WcT = ws+OFF_WC;
  float* yr  = ws+OFF_YR;
  float* wti = ws+OFF_YR;    // WTiv hosted in YR head; dead before k5 writes yr
  float* dxp = ws+OFF_DPX;
  float* bcp = ws+OFF_BC;

  k0_t     <<<64,256,0,stream>>>(inW, wti);
  k2_fused <<<896,256,0,stream>>>(zseq,aux,auxW,auxb,rmsw,wti,xpW,dtW,z,xsr,zg,WcT);
  k4b_xproj<<<512,384,0,stream>>>(xsr,convW,convb,WcT,dtb,dxp,bcp);
  k5_scan  <<<528,512,0,stream>>>(dxp,bcp,Alog,yr,outW,wot);
  k6_out   <<<512,256,0,stream>>>(yr,dxp,zg,Dp,wot,z,lnw,lnb,out);
}

// Round 18
// 174.546 us; speedup vs baseline: 1.0487x; 1.0397x over previous
//
#include <hip/hip_runtime.h>
#include <hip/hip_bf16.h>

#define B_SZ 4
#define T_SEQ 1024
#define DM 128
#define ED_ 256
#define NS 64
#define LOG2E 1.44269504088896340736f

// workspace layout (float elements). Total = 6,389,760 floats = 25.6 MB (accepted size).
// dxpT is TRANSPOSED [b][e][t] x {delta, delta*xs}; yrT is TRANSPOSED [b][e][t].
// WTiv (in_proj, float4-over-k x c) lives in the YR head: k0 -> k2, dead before k5 writes YR.
// wotv (out_proj, float4-over-k x d) lives in the XSR head: k5 extra blocks -> k6.
// R18: GEMM trio was GRID-LIMITED to 2-3 waves/SIMD (512 blocks x 4-6 waves).
// Widened blocks (k2: 512thr/1 col each; k4b: 768thr k-split; k6: 512thr k-split)
// double waves/SIMD at constant memory traffic.
#define OFF_Z      0u         /* 524288  f32  z (residual, read by K6)            */
#define OFF_ZG     524288u    /* 1048576 f32  gate (k2 -> k6)                     */
#define OFF_XSR    1572864u   /* 1048576 f32  conv input (k2 -> k4b); head=wotv   */
#define OFF_WC     2621440u   /* 98304   f32  Wcv[k4][c] float4-over-k weight     */
#define OFF_YR     2719744u   /* 1048576 f32  scan out [b][e][t]; head hosts WTiv */
#define OFF_DPX    3768320u   /* 2097152 f32  {delta, delta*xs} [b][e][t] pairs   */
#define OFF_BC     5865472u   /* 524288  f32  {B, C} [b][t][n] pairs (k4b -> k5)  */

__device__ __forceinline__ float sigmoidf_(float x){ return 1.f/(1.f+__expf(-x)); }
__device__ __forceinline__ float exp2_(float x){ return __builtin_amdgcn_exp2f(x); }
__device__ __forceinline__ float rlane_(float v, int l){
  return __int_as_float(__builtin_amdgcn_readlane(__float_as_int(v), l));
}

// Fused DPP add: p += dpp(p) in ONE instruction. bound_ctrl:0 => invalid lanes read 0.
#define DPPR(p, ctl) asm("v_add_f32_dpp %0, %0, %0 " ctl " row_mask:0xf bank_mask:0xf bound_ctrl:0" : "+v"(p))
#define DPP6(p) do{ DPPR(p,"row_shr:1"); DPPR(p,"row_shr:2"); DPPR(p,"row_shr:4"); \
                    DPPR(p,"row_shr:8"); DPPR(p,"row_bcast:15"); DPPR(p,"row_bcast:31"); }while(0)

// K0: build WTiv: float4[(k4*512)+c] = {W[c][4k4+0..3]}.
__global__ __launch_bounds__(256) void k0_t(const float* W, float* WTi){
  int k4 = blockIdx.x >> 1;               // 0..31
  int c  = (blockIdx.x & 1)*256 + threadIdx.x;
  float4 w = *(const float4*)&W[(size_t)c*128 + 4*k4];
  ((float4*)WTi)[k4*512 + c] = w;
}

// K2f: blocks 0..511: fused [z; RMSNorm] -> LDS, then in_proj GEMM via WTiv.
// NOW 512 threads: one column per thread (8 waves/block -> 4 waves/SIMD at
// grid 512, vs 2 before). blocks 512..895: build Wcv[k4][c] (first 256 thr).
__global__ __launch_bounds__(512,4) void k2_fused(const float* zseq, const float* aux, const float* auxW,
                                                const float* auxb, const float* rmsw, const float* WTi,
                                                const float* xprojW, const float* dtW,
                                                float* z, float* xsr, float* zg, float* WcT){
  if (blockIdx.x >= 512){
    if (threadIdx.x >= 256) return;
    int r = blockIdx.x - 512; int k = threadIdx.x;
    float v;
    if (r < 256){
      v = 0.f;
      #pragma unroll
      for (int j=0;j<8;j++) v += dtW[r*8+j] * xprojW[j*256+k];
    } else {
      v = xprojW[(8 + r-256)*256 + k];
    }
    WcT[((k>>2)*384 + r)*4 + (k&3)] = v;   // scalar store into float4-over-k slot (one-off)
    return;
  }
  __shared__ float at[128][8];
  int bt0 = blockIdx.x*8; int tid = threadIdx.x;
  {
    int r = tid>>6, l = tid&63;            // 8 rows x 64 lanes
    int bt = bt0 + r;
    float a0 = aux[bt*3+0], a1 = aux[bt*3+1], a2 = aux[bt*3+2];
    float zv[2]; float ssq = 0.f;
    #pragma unroll
    for (int j=0;j<2;j++){
      int d = l + 64*j;
      float v = zseq[bt*DM+d] + a0*auxW[d*3+0] + a1*auxW[d*3+1] + a2*auxW[d*3+2] + auxb[d];
      zv[j] = v; ssq += v*v;
    }
    #pragma unroll
    for (int m=32;m>=1;m>>=1) ssq += __shfl_xor(ssq, m);
    float rinv = rsqrtf(ssq*(1.f/DM) + 1e-5f);
    #pragma unroll
    for (int j=0;j<2;j++){
      int d = l + 64*j;
      z[bt*DM+d] = zv[j];
      at[d][r] = zv[j]*rinv*rmsw[d];
    }
  }
  __syncthreads();
  float acc[8];
  #pragma unroll
  for (int r=0;r<8;r++) acc[r]=0.f;
  int c0 = tid;                            // 0..511, one column each
  const float4* WTv = (const float4*)WTi;
  for (int k4=0;k4<32;k4++){
    float4 w = WTv[k4*512 + c0];           // coalesced 16B/lane, 4 k's
    float wa[4] = {w.x,w.y,w.z,w.w};
    #pragma unroll
    for (int kk=0;kk<4;kk++){
      float a[8];
      *(float4*)&a[0] = *(const float4*)&at[4*k4+kk][0];   // broadcast b128
      *(float4*)&a[4] = *(const float4*)&at[4*k4+kk][4];
      #pragma unroll
      for (int r=0;r<8;r++) acc[r] = fmaf(a[r], wa[kk], acc[r]);
    }
  }
  if (c0 < 256){
    #pragma unroll
    for (int r=0;r<8;r++) xsr[(bt0+r)*ED_ + c0] = acc[r];
  } else {
    int c1 = c0 - 256;
    #pragma unroll
    for (int r=0;r<8;r++) zg[(bt0+r)*ED_ + c1] = acc[r];
  }
}

// K4b: conv+SiLU staging, then x_proj GEMM with K-SPLIT: 768 threads, halves
// (waves 0-5 / 6-11) each do half the k4 range, LDS-combine. 6 waves/SIMD.
__global__ __launch_bounds__(768,6) void k4b_xproj(const float* xsr, const float* convW, const float* convb,
                                                 const float* WcT, const float* dtb,
                                                 float* dxp, float* bcf){
  __shared__ float at[256][8];
  __shared__ float pacc[384][8];
  int bt0 = blockIdx.x*8; int tid = threadIdx.x;
  for (int i=tid;i<2048;i+=768){
    int r=i>>8,k=i&255; int bt=bt0+r; int t = bt & (T_SEQ-1);
    float4 wv = *(const float4*)(convW + k*4);
    float s = convb[k];
    if (t>=3) s += xsr[(bt-3)*ED_+k]*wv.x;
    if (t>=2) s += xsr[(bt-2)*ED_+k]*wv.y;
    if (t>=1) s += xsr[(bt-1)*ED_+k]*wv.z;
    s += xsr[bt*ED_+k]*wv.w;
    at[k][r] = s * sigmoidf_(s);
  }
  __syncthreads();
  float acc[8];
  #pragma unroll
  for (int r=0;r<8;r++) acc[r]=0.f;
  int half = (tid >= 384);
  int c = half ? (tid - 384) : tid;        // 0..383, wave-uniform split
  const float4* Wv = (const float4*)WcT;
  int k40 = half ? 32 : 0;
  for (int kq=0;kq<32;kq++){
    int k4 = k40 + kq;
    float4 w = Wv[k4*384 + c];             // coalesced 16B/lane, 4 k's
    float wa[4] = {w.x,w.y,w.z,w.w};
    #pragma unroll
    for (int kk=0;kk<4;kk++){
      float a[8];
      *(float4*)&a[0] = *(const float4*)&at[4*k4+kk][0];   // broadcast
      *(float4*)&a[4] = *(const float4*)&at[4*k4+kk][4];
      #pragma unroll
      for (int r=0;r<8;r++) acc[r] = fmaf(a[r], wa[kk], acc[r]);
    }
  }
  if (half){
    #pragma unroll
    for (int r=0;r<8;r++) pacc[c][r] = acc[r];
  }
  __syncthreads();
  if (!half){
    #pragma unroll
    for (int r=0;r<8;r++) acc[r] += pacc[c][r];
    int b4 = bt0 >> 10, tb = bt0 & (T_SEQ-1);
    if (c < 256){
      float bcv = dtb[c];
      float2* pout = (float2*)dxp + (size_t)(b4*ED_ + c)*T_SEQ + tb;
      #pragma unroll
      for (int r=0;r<8;r++){
        float xv = acc[r] + bcv;
        float dv = (xv > 20.f) ? xv : log1pf(__expf(xv));
        pout[r] = make_float2(dv, dv * at[c][r]);   // {delta, delta*xs}
      }
    } else if (c < 320){
      #pragma unroll
      for (int r=0;r<8;r++) bcf[((size_t)(bt0+r)*NS + (c-256))*2 + 0] = acc[r];
    } else {
      #pragma unroll
      for (int r=0;r<8;r++) bcf[((size_t)(bt0+r)*NS + (c-320))*2 + 1] = acc[r];
    }
  }
}

// K5: bc-amortized chunked scan (R15/R14 config, measured best 43.6-44.4us):
// block = (b, 2 e's), 8 waves x 8 chunks of 128 t; one bc float2 load feeds
// 2 e's. Grid 512 scan blocks + 16 wotv-builder blocks. launch_bounds(512,4).
__global__ __launch_bounds__(512,4) void k5_scan(const float* dxpf, const float* bcf,
                                                  const float* Alog, float* yrT,
                                                  const float* outW, float* wot){
  if (blockIdx.x >= 512){
    int idx = (blockIdx.x - 512)*512 + threadIdx.x;   // 0..8191
    int k4 = idx >> 7;                                // 0..63
    int d  = idx & 127;
    float4 v = *(const float4*)&outW[(size_t)d*256 + 4*k4];  // 4 k's, aligned
    ((float4*)wot)[k4*128 + d] = v;                   // coalesced over d
    return;
  }
  __shared__ float lcar[7][2][64], lapr[7][2][64];
  __shared__ float red[8][16][2][66];
  int i  = blockIdx.x;
  int tid = threadIdx.x;
  int wv = tid >> 6;             // wave 0..7 == chunk index
  int n  = tid & 63;             // state index (lane)
  int x = i & 7;                 // XCD
  int r = i >> 3;                // 0..63
  int b = r & 3;
  int g = r >> 2;                // 0..15
  int eA = x*32 + g*2;
  int eB = eA + 1;
  const int CH = T_SEQ/8;        // 128
  int t0 = wv*CH;
  float A2A = -__expf(Alog[eA*NS+n]) * LOG2E;
  float A2B = -__expf(Alog[eB*NS+n]) * LOG2E;
  const float2* pdA = (const float2*)dxpf + (size_t)(b*ED_ + eA)*T_SEQ + t0;  // lane=t
  const float2* pdB = (const float2*)dxpf + (size_t)(b*ED_ + eB)*T_SEQ + t0;
  const float2* pbc = (const float2*)bcf  + (size_t)(b*T_SEQ + t0)*NS + n;    // lane=n
  float* pyA = yrT + (size_t)(b*ED_ + eA)*T_SEQ + t0;
  float* pyB = yrT + (size_t)(b*ED_ + eB)*T_SEQ + t0;

  // ---- phase 1: carry-only scan (waves 0..6; wave 7's carry unused)
  if (wv < 7){
    float hA=0.f, hB=0.f, SsA=0.f, SsB=0.f;
    float2 dxcA = pdA[n], dxcB = pdB[n];
    for (int sb=0; sb<CH; sb+=64){
      float2 dxnA = dxcA, dxnB = dxcB;
      if (sb+64 < CH){ dxnA = pdA[sb+64+n]; dxnB = pdB[sb+64+n]; }
      float svA = dxcA.x; DPP6(svA); SsA += rlane_(svA, 63);
      float svB = dxcB.x; DPP6(svB); SsB += rlane_(svB, 63);
      float bA[8], bBv[8];
      #pragma unroll
      for (int j=0;j<8;j++) bA[j] = pbc[(sb+j)*NS].x;
      #pragma unroll
      for (int bb=0; bb<64; bb+=16){
        #pragma unroll
        for (int j=0;j<8;j++) bBv[j] = pbc[(sb+bb+8+j)*NS].x;
        #pragma unroll
        for (int j=0;j<8;j++){
          float sdA = rlane_(dxcA.x, bb+j), suA = rlane_(dxcA.y, bb+j);
          hA = fmaf(exp2_(sdA*A2A), hA, suA*bA[j]);
          float sdB = rlane_(dxcB.x, bb+j), suB = rlane_(dxcB.y, bb+j);
          hB = fmaf(exp2_(sdB*A2B), hB, suB*bA[j]);
        }
        if (bb+16 < 64){
          #pragma unroll
          for (int j=0;j<8;j++) bA[j] = pbc[(sb+bb+16+j)*NS].x;
        }
        #pragma unroll
        for (int j=0;j<8;j++){
          float sdA = rlane_(dxcA.x, bb+8+j), suA = rlane_(dxcA.y, bb+8+j);
          hA = fmaf(exp2_(sdA*A2A), hA, suA*bBv[j]);
          float sdB = rlane_(dxcB.x, bb+8+j), suB = rlane_(dxcB.y, bb+8+j);
          hB = fmaf(exp2_(sdB*A2B), hB, suB*bBv[j]);
        }
      }
      dxcA = dxnA; dxcB = dxnB;
    }
    lcar[wv][0][n] = hA;  lapr[wv][0][n] = exp2_(A2A*SsA);
    lcar[wv][1][n] = hB;  lapr[wv][1][n] = exp2_(A2B*SsB);
  }
  __syncthreads();

  // ---- combine: h_in for this wave's chunk (both e's)
  float hA = 0.f, hB = 0.f;
  #pragma unroll
  for (int q=0;q<7;q++) if (wv > q){
    hA = fmaf(lapr[q][0][n], hA, lcar[q][0][n]);
    hB = fmaf(lapr[q][1][n], hB, lcar[q][1][n]);
  }

  // ---- phase 2: full output scan, shared bc load feeds both e's
  {
    float2 dxcA = pdA[n], dxcB = pdB[n];
    int ri = n & 31, hs = n >> 5;
    int eh = ri >> 4, tr = ri & 15;
    const float2* rp = (const float2*)&red[wv][tr][eh][hs*32];
    float* pyE = eh ? pyB : pyA;
    for (int sb=0; sb<CH; sb+=64){
      float2 dxnA = dxcA, dxnB = dxcB;
      if (sb+64 < CH){ dxnA = pdA[sb+64+n]; dxnB = pdB[sb+64+n]; }
      float2 cA[8], cB[8];
      #pragma unroll
      for (int j=0;j<8;j++) cA[j] = pbc[(sb+j)*NS];
      #pragma unroll
      for (int bb=0; bb<64; bb+=16){
        #pragma unroll
        for (int j=0;j<8;j++) cB[j] = pbc[(sb+bb+8+j)*NS];
        #pragma unroll
        for (int j=0;j<8;j++){
          float sdA = rlane_(dxcA.x, bb+j), suA = rlane_(dxcA.y, bb+j);
          hA = fmaf(exp2_(sdA*A2A), hA, suA*cA[j].x);
          red[wv][j][0][n] = hA*cA[j].y;
          float sdB = rlane_(dxcB.x, bb+j), suB = rlane_(dxcB.y, bb+j);
          hB = fmaf(exp2_(sdB*A2B), hB, suB*cA[j].x);
          red[wv][j][1][n] = hB*cA[j].y;
        }
        if (bb+16 < 64){
          #pragma unroll
          for (int j=0;j<8;j++) cA[j] = pbc[(sb+bb+16+j)*NS];
        }
        #pragma unroll
        for (int j=0;j<8;j++){
          float sdA = rlane_(dxcA.x, bb+8+j), suA = rlane_(dxcA.y, bb+8+j);
          hA = fmaf(exp2_(sdA*A2A), hA, suA*cB[j].x);
          red[wv][8+j][0][n] = hA*cB[j].y;
          float sdB = rlane_(dxcB.x, bb+8+j), suB = rlane_(dxcB.y, bb+8+j);
          hB = fmaf(exp2_(sdB*A2B), hB, suB*cB[j].x);
          red[wv][8+j][1][n] = hB*cB[j].y;
        }
        // transpose-reduce the 16t x 2e tile (same-wave DS ops are in-order)
        float s = 0.f;
        #pragma unroll
        for (int jj=0;jj<16;jj++){ float2 v = rp[jj]; s += v.x + v.y; }
        s += __shfl_xor(s, 32);
        if (n < 32) pyE[sb + bb + tr] = s;
      }
      dxcA = dxnA; dxcB = dxnB;
    }
  }
}

// K6: stage yrT + xs from dxpT via LDS; gate; out_proj GEMM with K-SPLIT
// (512 threads: quads 0-1 = k4 0..31, quads 2-3 = k4 32..63, LDS-combine);
// then LayerNorm. 4 waves/SIMD at grid 512 (vs 2 before).
__global__ __launch_bounds__(512,4) void k6_out(const float* yrT, const float* dxpf, const float* zg,
                                               const float* Dp, const float* wot, const float* z,
                                               const float* lnw, const float* lnb, float* out){
  __shared__ float yt[256][8];
  __shared__ float xst[256][8];
  __shared__ float pacc[256][4];
  __shared__ float psum[4][4], psq[4][4];
  int bt0 = blockIdx.x*8; int tid = threadIdx.x;
  int b4 = bt0 >> 10, tb = bt0 & (T_SEQ-1);
  int el = tid>>3, tl = tid&7;             // el 0..63
  #pragma unroll
  for (int gg=0; gg<4; gg++){
    int ee = el + gg*64;
    size_t base = (size_t)(b4*ED_ + ee)*T_SEQ + tb + tl;
    float2 du = ((const float2*)dxpf)[base];
    yt[ee][tl]  = yrT[base];
    xst[ee][tl] = du.y / du.x;        // xs = (delta*xs)/delta; delta >= softplus(-4) ~ 0.018
  }
  __syncthreads();
  for (int i=tid;i<2048;i+=512){
    int rr=i>>8, k=i&255; int bt=bt0+rr;
    float zgv = zg[bt*ED_ + k];
    float yv  = yt[k][rr] + Dp[k]*xst[k][rr];
    yt[k][rr] = yv * zgv * sigmoidf_(zgv);
  }
  __syncthreads();
  int d = tid & 127;
  int quad = tid >> 7;                     // 0..3
  int gdx = quad & 1, half = quad >> 1;
  float acc[4] = {0.f,0.f,0.f,0.f};
  const float4* Wv = (const float4*)wot;
  int k40 = half ? 32 : 0;
  for (int kq=0;kq<32;kq++){
    int k4 = k40 + kq;
    float4 w = Wv[k4*128 + d];             // coalesced 16B/lane, 4 k's
    int k = k4*4;
    float4 q0 = *(const float4*)&yt[k+0][gdx*4];   // broadcast
    float4 q1 = *(const float4*)&yt[k+1][gdx*4];
    float4 q2 = *(const float4*)&yt[k+2][gdx*4];
    float4 q3 = *(const float4*)&yt[k+3][gdx*4];
    acc[0] = fmaf(q0.x,w.x,acc[0]); acc[1] = fmaf(q0.y,w.x,acc[1]);
    acc[2] = fmaf(q0.z,w.x,acc[2]); acc[3] = fmaf(q0.w,w.x,acc[3]);
    acc[0] = fmaf(q1.x,w.y,acc[0]); acc[1] = fmaf(q1.y,w.y,acc[1]);
    acc[2] = fmaf(q1.z,w.y,acc[2]); acc[3] = fmaf(q1.w,w.y,acc[3]);
    acc[0] = fmaf(q2.x,w.z,acc[0]); acc[1] = fmaf(q2.y,w.z,acc[1]);
    acc[2] = fmaf(q2.z,w.z,acc[2]); acc[3] = fmaf(q2.w,w.z,acc[3]);
    acc[0] = fmaf(q3.x,w.w,acc[0]); acc[1] = fmaf(q3.y,w.w,acc[1]);
    acc[2] = fmaf(q3.z,w.w,acc[2]); acc[3] = fmaf(q3.w,w.w,acc[3]);
  }
  if (half){
    #pragma unroll
    for (int j=0;j<4;j++) pacc[gdx*128+d][j] = acc[j];
  }
  __syncthreads();
  float val[4];
  if (!half){
    #pragma unroll
    for (int j=0;j<4;j++) acc[j] += pacc[gdx*128+d][j];
    #pragma unroll
    for (int j=0;j<4;j++){
      int bt = bt0 + gdx*4 + j;
      val[j] = acc[j] + 2.f*z[bt*DM + d];
    }
    int w_id = tid>>6;
    #pragma unroll
    for (int j=0;j<4;j++){
      float s = val[j], q = val[j]*val[j];
      #pragma unroll
      for (int off=32; off>=1; off>>=1){ s += __shfl_down(s, off); q += __shfl_down(q, off); }
      if ((tid&63)==0){ psum[w_id][j]=s; psq[w_id][j]=q; }
    }
  }
  __syncthreads();
  if (!half){
    float lw = lnw[d], lb = lnb[d];
    #pragma unroll
    for (int j=0;j<4;j++){
      int bt = bt0 + gdx*4 + j;
      float sum = psum[gdx*2][j] + psum[gdx*2+1][j];
      float sq  = psq [gdx*2][j] + psq [gdx*2+1][j];
      float mu  = sum*(1.f/DM);
      float var = sq*(1.f/DM) - mu*mu;
      float inv = rsqrtf(var + 1e-5f);
      out[bt*DM + d] = (val[j]-mu)*inv*lw + lb;
    }
  }
}

extern "C" void kernel_launch(void* const* d_in, const int* in_sizes, int n_in,
                              void* d_out, int out_size, void* d_ws, size_t ws_size,
                              hipStream_t stream){
  const float* zseq = (const float*)d_in[0];
  const float* aux  = (const float*)d_in[1];
  const float* auxW = (const float*)d_in[2];
  const float* auxb = (const float*)d_in[3];
  const float* lnw  = (const float*)d_in[4];
  const float* lnb  = (const float*)d_in[5];
  const float* rmsw = (const float*)d_in[6];
  const float* inW  = (const float*)d_in[7];
  const float* convW= (const float*)d_in[8];
  const float* convb= (const float*)d_in[9];
  const float* xpW  = (const float*)d_in[10];
  const float* dtW  = (const float*)d_in[11];
  const float* dtb  = (const float*)d_in[12];
  const float* Alog = (const float*)d_in[13];
  const float* Dp   = (const float*)d_in[14];
  const float* outW = (const float*)d_in[15];
  float* out = (float*)d_out;
  float* ws = (float*)d_ws;

  float* z   = ws+OFF_Z;
  float* zg  = ws+OFF_ZG;
  float* xsr = ws+OFF_XSR;
  float* wot = ws+OFF_XSR;   // wotv hosted in XSR head; xsr dead after k4b
  float* WcT = ws+OFF_WC;
  float* yr  = ws+OFF_YR;
  float* wti = ws+OFF_YR;    // WTiv hosted in YR head; dead before k5 writes yr
  float* dxp = ws+OFF_DPX;
  float* bcp = ws+OFF_BC;

  k0_t     <<<64,256,0,stream>>>(inW, wti);
  k2_fused <<<896,512,0,stream>>>(zseq,aux,auxW,auxb,rmsw,wti,xpW,dtW,z,xsr,zg,WcT);
  k4b_xproj<<<512,768,0,stream>>>(xsr,convW,convb,WcT,dtb,dxp,bcp);
  k5_scan  <<<528,512,0,stream>>>(dxp,bcp,Alog,yr,outW,wot);
  k6_out   <<<512,512,0,stream>>>(yr,dxp,zg,Dp,wot,z,lnw,lnb,out);
}

// Round 19
// 172.467 us; speedup vs baseline: 1.0613x; 1.0121x over previous
//
#include <hip/hip_runtime.h>
#include <hip/hip_bf16.h>

#define B_SZ 4
#define T_SEQ 1024
#define DM 128
#define ED_ 256
#define NS 64
#define LOG2E 1.44269504088896340736f

// workspace layout (float elements). Total = 6,389,760 floats = 25.6 MB (accepted size).
// dxpT is TRANSPOSED [b][e][t] x {delta, delta*xs}; yrT is TRANSPOSED [b][e][t].
// WTiv (in_proj, float4-over-k x c) lives in the YR head: k0 -> k2, dead before k5 writes YR.
// wotv (out_proj, float4-over-k x d) lives in the XSR head: k5 extra blocks -> k6.
// R19: push k2/k6 to full 32 waves/CU (1024-thr blocks, k-split + LDS combine).
// R18 established the trio was occupancy-limited; fills (~43us, harness) are fixed.
#define OFF_Z      0u         /* 524288  f32  z (residual, read by K6)            */
#define OFF_ZG     524288u    /* 1048576 f32  gate (k2 -> k6)                     */
#define OFF_XSR    1572864u   /* 1048576 f32  conv input (k2 -> k4b); head=wotv   */
#define OFF_WC     2621440u   /* 98304   f32  Wcv[k4][c] float4-over-k weight     */
#define OFF_YR     2719744u   /* 1048576 f32  scan out [b][e][t]; head hosts WTiv */
#define OFF_DPX    3768320u   /* 2097152 f32  {delta, delta*xs} [b][e][t] pairs   */
#define OFF_BC     5865472u   /* 524288  f32  {B, C} [b][t][n] pairs (k4b -> k5)  */

__device__ __forceinline__ float sigmoidf_(float x){ return 1.f/(1.f+__expf(-x)); }
__device__ __forceinline__ float exp2_(float x){ return __builtin_amdgcn_exp2f(x); }
__device__ __forceinline__ float rlane_(float v, int l){
  return __int_as_float(__builtin_amdgcn_readlane(__float_as_int(v), l));
}

// Fused DPP add: p += dpp(p) in ONE instruction. bound_ctrl:0 => invalid lanes read 0.
#define DPPR(p, ctl) asm("v_add_f32_dpp %0, %0, %0 " ctl " row_mask:0xf bank_mask:0xf bound_ctrl:0" : "+v"(p))
#define DPP6(p) do{ DPPR(p,"row_shr:1"); DPPR(p,"row_shr:2"); DPPR(p,"row_shr:4"); \
                    DPPR(p,"row_shr:8"); DPPR(p,"row_bcast:15"); DPPR(p,"row_bcast:31"); }while(0)

// K0: build WTiv: float4[(k4*512)+c] = {W[c][4k4+0..3]}.
__global__ __launch_bounds__(256) void k0_t(const float* W, float* WTi){
  int k4 = blockIdx.x >> 1;               // 0..31
  int c  = (blockIdx.x & 1)*256 + threadIdx.x;
  float4 w = *(const float4*)&W[(size_t)c*128 + 4*k4];
  ((float4*)WTi)[k4*512 + c] = w;
}

// K2f: blocks 0..511: fused [z; RMSNorm] -> LDS (first 512 threads), then
// in_proj GEMM with 2-WAY K-SPLIT over 1024 threads (halves do k4 0-15/16-31,
// LDS-combine). 16 waves/block x 2 blocks/CU = 32 waves/CU (was 16).
// blocks 512..607: dense Wc builder (4 (r,k)-pairs per thread-row group).
__global__ __launch_bounds__(1024,2) void k2_fused(const float* zseq, const float* aux, const float* auxW,
                                                const float* auxb, const float* rmsw, const float* WTi,
                                                const float* xprojW, const float* dtW,
                                                float* z, float* xsr, float* zg, float* WcT){
  if (blockIdx.x >= 512){
    int r = (blockIdx.x - 512)*4 + (threadIdx.x >> 8);   // 0..383
    int k = threadIdx.x & 255;
    float v;
    if (r < 256){
      v = 0.f;
      #pragma unroll
      for (int j=0;j<8;j++) v += dtW[r*8+j] * xprojW[j*256+k];
    } else {
      v = xprojW[(8 + r-256)*256 + k];
    }
    WcT[((k>>2)*384 + r)*4 + (k&3)] = v;   // scalar store into float4-over-k slot (one-off)
    return;
  }
  __shared__ float at[128][8];
  __shared__ float pacc[512][8];
  int bt0 = blockIdx.x*8; int tid = threadIdx.x;
  if (tid < 512){
    int r = tid>>6, l = tid&63;            // 8 rows x 64 lanes
    int bt = bt0 + r;
    float a0 = aux[bt*3+0], a1 = aux[bt*3+1], a2 = aux[bt*3+2];
    float zv[2]; float ssq = 0.f;
    #pragma unroll
    for (int j=0;j<2;j++){
      int d = l + 64*j;
      float v = zseq[bt*DM+d] + a0*auxW[d*3+0] + a1*auxW[d*3+1] + a2*auxW[d*3+2] + auxb[d];
      zv[j] = v; ssq += v*v;
    }
    #pragma unroll
    for (int m=32;m>=1;m>>=1) ssq += __shfl_xor(ssq, m);
    float rinv = rsqrtf(ssq*(1.f/DM) + 1e-5f);
    #pragma unroll
    for (int j=0;j<2;j++){
      int d = l + 64*j;
      z[bt*DM+d] = zv[j];
      at[d][r] = zv[j]*rinv*rmsw[d];
    }
  }
  __syncthreads();
  float acc[8];
  #pragma unroll
  for (int r=0;r<8;r++) acc[r]=0.f;
  int c0 = tid & 511;
  int half = tid >> 9;                     // 0 or 1, wave-uniform
  const float4* WTv = (const float4*)WTi;
  int k40 = half ? 16 : 0;
  for (int kq=0;kq<16;kq++){
    int k4 = k40 + kq;
    float4 w = WTv[k4*512 + c0];           // coalesced 16B/lane, 4 k's
    float wa[4] = {w.x,w.y,w.z,w.w};
    #pragma unroll
    for (int kk=0;kk<4;kk++){
      float a[8];
      *(float4*)&a[0] = *(const float4*)&at[4*k4+kk][0];   // broadcast b128
      *(float4*)&a[4] = *(const float4*)&at[4*k4+kk][4];
      #pragma unroll
      for (int r=0;r<8;r++) acc[r] = fmaf(a[r], wa[kk], acc[r]);
    }
  }
  if (half){
    #pragma unroll
    for (int r=0;r<8;r++) pacc[c0][r] = acc[r];
  }
  __syncthreads();
  if (!half){
    #pragma unroll
    for (int r=0;r<8;r++) acc[r] += pacc[c0][r];
    if (c0 < 256){
      #pragma unroll
      for (int r=0;r<8;r++) xsr[(bt0+r)*ED_ + c0] = acc[r];
    } else {
      int c1 = c0 - 256;
      #pragma unroll
      for (int r=0;r<8;r++) zg[(bt0+r)*ED_ + c1] = acc[r];
    }
  }
}

// K4b: conv+SiLU staging, then x_proj GEMM with K-SPLIT: 768 threads, halves
// (waves 0-5 / 6-11) each do half the k4 range, LDS-combine. 6 waves/SIMD.
__global__ __launch_bounds__(768,6) void k4b_xproj(const float* xsr, const float* convW, const float* convb,
                                                 const float* WcT, const float* dtb,
                                                 float* dxp, float* bcf){
  __shared__ float at[256][8];
  __shared__ float pacc[384][8];
  int bt0 = blockIdx.x*8; int tid = threadIdx.x;
  for (int i=tid;i<2048;i+=768){
    int r=i>>8,k=i&255; int bt=bt0+r; int t = bt & (T_SEQ-1);
    float4 wv = *(const float4*)(convW + k*4);
    float s = convb[k];
    if (t>=3) s += xsr[(bt-3)*ED_+k]*wv.x;
    if (t>=2) s += xsr[(bt-2)*ED_+k]*wv.y;
    if (t>=1) s += xsr[(bt-1)*ED_+k]*wv.z;
    s += xsr[bt*ED_+k]*wv.w;
    at[k][r] = s * sigmoidf_(s);
  }
  __syncthreads();
  float acc[8];
  #pragma unroll
  for (int r=0;r<8;r++) acc[r]=0.f;
  int half = (tid >= 384);
  int c = half ? (tid - 384) : tid;        // 0..383, wave-uniform split
  const float4* Wv = (const float4*)WcT;
  int k40 = half ? 32 : 0;
  for (int kq=0;kq<32;kq++){
    int k4 = k40 + kq;
    float4 w = Wv[k4*384 + c];             // coalesced 16B/lane, 4 k's
    float wa[4] = {w.x,w.y,w.z,w.w};
    #pragma unroll
    for (int kk=0;kk<4;kk++){
      float a[8];
      *(float4*)&a[0] = *(const float4*)&at[4*k4+kk][0];   // broadcast
      *(float4*)&a[4] = *(const float4*)&at[4*k4+kk][4];
      #pragma unroll
      for (int r=0;r<8;r++) acc[r] = fmaf(a[r], wa[kk], acc[r]);
    }
  }
  if (half){
    #pragma unroll
    for (int r=0;r<8;r++) pacc[c][r] = acc[r];
  }
  __syncthreads();
  if (!half){
    #pragma unroll
    for (int r=0;r<8;r++) acc[r] += pacc[c][r];
    int b4 = bt0 >> 10, tb = bt0 & (T_SEQ-1);
    if (c < 256){
      float bcv = dtb[c];
      float2* pout = (float2*)dxp + (size_t)(b4*ED_ + c)*T_SEQ + tb;
      #pragma unroll
      for (int r=0;r<8;r++){
        float xv = acc[r] + bcv;
        float dv = (xv > 20.f) ? xv : log1pf(__expf(xv));
        pout[r] = make_float2(dv, dv * at[c][r]);   // {delta, delta*xs}
      }
    } else if (c < 320){
      #pragma unroll
      for (int r=0;r<8;r++) bcf[((size_t)(bt0+r)*NS + (c-256))*2 + 0] = acc[r];
    } else {
      #pragma unroll
      for (int r=0;r<8;r++) bcf[((size_t)(bt0+r)*NS + (c-320))*2 + 1] = acc[r];
    }
  }
}

// K5: bc-amortized chunked scan (R15/R14 config, measured best 43.6-44.4us):
// block = (b, 2 e's), 8 waves x 8 chunks of 128 t; one bc float2 load feeds
// 2 e's. Grid 512 scan blocks + 16 wotv-builder blocks. launch_bounds(512,4).
__global__ __launch_bounds__(512,4) void k5_scan(const float* dxpf, const float* bcf,
                                                  const float* Alog, float* yrT,
                                                  const float* outW, float* wot){
  if (blockIdx.x >= 512){
    int idx = (blockIdx.x - 512)*512 + threadIdx.x;   // 0..8191
    int k4 = idx >> 7;                                // 0..63
    int d  = idx & 127;
    float4 v = *(const float4*)&outW[(size_t)d*256 + 4*k4];  // 4 k's, aligned
    ((float4*)wot)[k4*128 + d] = v;                   // coalesced over d
    return;
  }
  __shared__ float lcar[7][2][64], lapr[7][2][64];
  __shared__ float red[8][16][2][66];
  int i  = blockIdx.x;
  int tid = threadIdx.x;
  int wv = tid >> 6;             // wave 0..7 == chunk index
  int n  = tid & 63;             // state index (lane)
  int x = i & 7;                 // XCD
  int r = i >> 3;                // 0..63
  int b = r & 3;
  int g = r >> 2;                // 0..15
  int eA = x*32 + g*2;
  int eB = eA + 1;
  const int CH = T_SEQ/8;        // 128
  int t0 = wv*CH;
  float A2A = -__expf(Alog[eA*NS+n]) * LOG2E;
  float A2B = -__expf(Alog[eB*NS+n]) * LOG2E;
  const float2* pdA = (const float2*)dxpf + (size_t)(b*ED_ + eA)*T_SEQ + t0;  // lane=t
  const float2* pdB = (const float2*)dxpf + (size_t)(b*ED_ + eB)*T_SEQ + t0;
  const float2* pbc = (const float2*)bcf  + (size_t)(b*T_SEQ + t0)*NS + n;    // lane=n
  float* pyA = yrT + (size_t)(b*ED_ + eA)*T_SEQ + t0;
  float* pyB = yrT + (size_t)(b*ED_ + eB)*T_SEQ + t0;

  // ---- phase 1: carry-only scan (waves 0..6; wave 7's carry unused)
  if (wv < 7){
    float hA=0.f, hB=0.f, SsA=0.f, SsB=0.f;
    float2 dxcA = pdA[n], dxcB = pdB[n];
    for (int sb=0; sb<CH; sb+=64){
      float2 dxnA = dxcA, dxnB = dxcB;
      if (sb+64 < CH){ dxnA = pdA[sb+64+n]; dxnB = pdB[sb+64+n]; }
      float svA = dxcA.x; DPP6(svA); SsA += rlane_(svA, 63);
      float svB = dxcB.x; DPP6(svB); SsB += rlane_(svB, 63);
      float bA[8], bBv[8];
      #pragma unroll
      for (int j=0;j<8;j++) bA[j] = pbc[(sb+j)*NS].x;
      #pragma unroll
      for (int bb=0; bb<64; bb+=16){
        #pragma unroll
        for (int j=0;j<8;j++) bBv[j] = pbc[(sb+bb+8+j)*NS].x;
        #pragma unroll
        for (int j=0;j<8;j++){
          float sdA = rlane_(dxcA.x, bb+j), suA = rlane_(dxcA.y, bb+j);
          hA = fmaf(exp2_(sdA*A2A), hA, suA*bA[j]);
          float sdB = rlane_(dxcB.x, bb+j), suB = rlane_(dxcB.y, bb+j);
          hB = fmaf(exp2_(sdB*A2B), hB, suB*bA[j]);
        }
        if (bb+16 < 64){
          #pragma unroll
          for (int j=0;j<8;j++) bA[j] = pbc[(sb+bb+16+j)*NS].x;
        }
        #pragma unroll
        for (int j=0;j<8;j++){
          float sdA = rlane_(dxcA.x, bb+8+j), suA = rlane_(dxcA.y, bb+8+j);
          hA = fmaf(exp2_(sdA*A2A), hA, suA*bBv[j]);
          float sdB = rlane_(dxcB.x, bb+8+j), suB = rlane_(dxcB.y, bb+8+j);
          hB = fmaf(exp2_(sdB*A2B), hB, suB*bBv[j]);
        }
      }
      dxcA = dxnA; dxcB = dxnB;
    }
    lcar[wv][0][n] = hA;  lapr[wv][0][n] = exp2_(A2A*SsA);
    lcar[wv][1][n] = hB;  lapr[wv][1][n] = exp2_(A2B*SsB);
  }
  __syncthreads();

  // ---- combine: h_in for this wave's chunk (both e's)
  float hA = 0.f, hB = 0.f;
  #pragma unroll
  for (int q=0;q<7;q++) if (wv > q){
    hA = fmaf(lapr[q][0][n], hA, lcar[q][0][n]);
    hB = fmaf(lapr[q][1][n], hB, lcar[q][1][n]);
  }

  // ---- phase 2: full output scan, shared bc load feeds both e's
  {
    float2 dxcA = pdA[n], dxcB = pdB[n];
    int ri = n & 31, hs = n >> 5;
    int eh = ri >> 4, tr = ri & 15;
    const float2* rp = (const float2*)&red[wv][tr][eh][hs*32];
    float* pyE = eh ? pyB : pyA;
    for (int sb=0; sb<CH; sb+=64){
      float2 dxnA = dxcA, dxnB = dxcB;
      if (sb+64 < CH){ dxnA = pdA[sb+64+n]; dxnB = pdB[sb+64+n]; }
      float2 cA[8], cB[8];
      #pragma unroll
      for (int j=0;j<8;j++) cA[j] = pbc[(sb+j)*NS];
      #pragma unroll
      for (int bb=0; bb<64; bb+=16){
        #pragma unroll
        for (int j=0;j<8;j++) cB[j] = pbc[(sb+bb+8+j)*NS];
        #pragma unroll
        for (int j=0;j<8;j++){
          float sdA = rlane_(dxcA.x, bb+j), suA = rlane_(dxcA.y, bb+j);
          hA = fmaf(exp2_(sdA*A2A), hA, suA*cA[j].x);
          red[wv][j][0][n] = hA*cA[j].y;
          float sdB = rlane_(dxcB.x, bb+j), suB = rlane_(dxcB.y, bb+j);
          hB = fmaf(exp2_(sdB*A2B), hB, suB*cA[j].x);
          red[wv][j][1][n] = hB*cA[j].y;
        }
        if (bb+16 < 64){
          #pragma unroll
          for (int j=0;j<8;j++) cA[j] = pbc[(sb+bb+16+j)*NS];
        }
        #pragma unroll
        for (int j=0;j<8;j++){
          float sdA = rlane_(dxcA.x, bb+8+j), suA = rlane_(dxcA.y, bb+8+j);
          hA = fmaf(exp2_(sdA*A2A), hA, suA*cB[j].x);
          red[wv][8+j][0][n] = hA*cB[j].y;
          float sdB = rlane_(dxcB.x, bb+8+j), suB = rlane_(dxcB.y, bb+8+j);
          hB = fmaf(exp2_(sdB*A2B), hB, suB*cB[j].x);
          red[wv][8+j][1][n] = hB*cB[j].y;
        }
        // transpose-reduce the 16t x 2e tile (same-wave DS ops are in-order)
        float s = 0.f;
        #pragma unroll
        for (int jj=0;jj<16;jj++){ float2 v = rp[jj]; s += v.x + v.y; }
        s += __shfl_xor(s, 32);
        if (n < 32) pyE[sb + bb + tr] = s;
      }
      dxcA = dxnA; dxcB = dxnB;
    }
  }
}

// K6: stage yrT + xs from dxpT via LDS; gate; out_proj GEMM with 4-WAY K-SPLIT
// (1024 threads: 8 groups (gdx 0-1, ks 0-3), 16 k4 each; pacc[3] LDS-combine);
// then LayerNorm on group ks=0. 16 waves/block x 2 blocks/CU = 32 waves/CU.
__global__ __launch_bounds__(1024,2) void k6_out(const float* yrT, const float* dxpf, const float* zg,
                                               const float* Dp, const float* wot, const float* z,
                                               const float* lnw, const float* lnb, float* out){
  __shared__ float yt[256][8];
  __shared__ float xst[256][8];
  __shared__ float pacc[3][256][4];
  __shared__ float psum[4][4], psq[4][4];
  int bt0 = blockIdx.x*8; int tid = threadIdx.x;
  int b4 = bt0 >> 10, tb = bt0 & (T_SEQ-1);
  int el = tid>>3, tl = tid&7;             // el 0..127
  #pragma unroll
  for (int gg=0; gg<2; gg++){
    int ee = el + gg*128;
    size_t base = (size_t)(b4*ED_ + ee)*T_SEQ + tb + tl;
    float2 du = ((const float2*)dxpf)[base];
    yt[ee][tl]  = yrT[base];
    xst[ee][tl] = du.y / du.x;        // xs = (delta*xs)/delta; delta >= softplus(-4) ~ 0.018
  }
  __syncthreads();
  for (int i=tid;i<2048;i+=1024){
    int rr=i>>8, k=i&255; int bt=bt0+rr;
    float zgv = zg[bt*ED_ + k];
    float yv  = yt[k][rr] + Dp[k]*xst[k][rr];
    yt[k][rr] = yv * zgv * sigmoidf_(zgv);
  }
  __syncthreads();
  int d = tid & 127;
  int grp = tid >> 7;                      // 0..7
  int gdx = grp & 1, ks = grp >> 1;        // ks 0..3
  float acc[4] = {0.f,0.f,0.f,0.f};
  const float4* Wv = (const float4*)wot;
  int k40 = ks * 16;
  for (int kq=0;kq<16;kq++){
    int k4 = k40 + kq;
    float4 w = Wv[k4*128 + d];             // coalesced 16B/lane, 4 k's
    int k = k4*4;
    float4 q0 = *(const float4*)&yt[k+0][gdx*4];   // broadcast
    float4 q1 = *(const float4*)&yt[k+1][gdx*4];
    float4 q2 = *(const float4*)&yt[k+2][gdx*4];
    float4 q3 = *(const float4*)&yt[k+3][gdx*4];
    acc[0] = fmaf(q0.x,w.x,acc[0]); acc[1] = fmaf(q0.y,w.x,acc[1]);
    acc[2] = fmaf(q0.z,w.x,acc[2]); acc[3] = fmaf(q0.w,w.x,acc[3]);
    acc[0] = fmaf(q1.x,w.y,acc[0]); acc[1] = fmaf(q1.y,w.y,acc[1]);
    acc[2] = fmaf(q1.z,w.y,acc[2]); acc[3] = fmaf(q1.w,w.y,acc[3]);
    acc[0] = fmaf(q2.x,w.z,acc[0]); acc[1] = fmaf(q2.y,w.z,acc[1]);
    acc[2] = fmaf(q2.z,w.z,acc[2]); acc[3] = fmaf(q2.w,w.z,acc[3]);
    acc[0] = fmaf(q3.x,w.w,acc[0]); acc[1] = fmaf(q3.y,w.w,acc[1]);
    acc[2] = fmaf(q3.z,w.w,acc[2]); acc[3] = fmaf(q3.w,w.w,acc[3]);
  }
  if (ks){
    #pragma unroll
    for (int j=0;j<4;j++) pacc[ks-1][gdx*128+d][j] = acc[j];
  }
  __syncthreads();
  float val[4];
  if (!ks){
    #pragma unroll
    for (int s2=0;s2<3;s2++)
      #pragma unroll
      for (int j=0;j<4;j++) acc[j] += pacc[s2][gdx*128+d][j];
    #pragma unroll
    for (int j=0;j<4;j++){
      int bt = bt0 + gdx*4 + j;
      val[j] = acc[j] + 2.f*z[bt*DM + d];
    }
    int w_id = tid>>6;                     // 0..3 (tid<256 here)
    #pragma unroll
    for (int j=0;j<4;j++){
      float s = val[j], q = val[j]*val[j];
      #pragma unroll
      for (int off=32; off>=1; off>>=1){ s += __shfl_down(s, off); q += __shfl_down(q, off); }
      if ((tid&63)==0){ psum[w_id][j]=s; psq[w_id][j]=q; }
    }
  }
  __syncthreads();
  if (!ks){
    float lw = lnw[d], lb = lnb[d];
    #pragma unroll
    for (int j=0;j<4;j++){
      int bt = bt0 + gdx*4 + j;
      float sum = psum[gdx*2][j] + psum[gdx*2+1][j];
      float sq  = psq [gdx*2][j] + psq [gdx*2+1][j];
      float mu  = sum*(1.f/DM);
      float var = sq*(1.f/DM) - mu*mu;
      float inv = rsqrtf(var + 1e-5f);
      out[bt*DM + d] = (val[j]-mu)*inv*lw + lb;
    }
  }
}

extern "C" void kernel_launch(void* const* d_in, const int* in_sizes, int n_in,
                              void* d_out, int out_size, void* d_ws, size_t ws_size,
                              hipStream_t stream){
  const float* zseq = (const float*)d_in[0];
  const float* aux  = (const float*)d_in[1];
  const float* auxW = (const float*)d_in[2];
  const float* auxb = (const float*)d_in[3];
  const float* lnw  = (const float*)d_in[4];
  const float* lnb  = (const float*)d_in[5];
  const float* rmsw = (const float*)d_in[6];
  const float* inW  = (const float*)d_in[7];
  const float* convW= (const float*)d_in[8];
  const float* convb= (const float*)d_in[9];
  const float* xpW  = (const float*)d_in[10];
  const float* dtW  = (const float*)d_in[11];
  const float* dtb  = (const float*)d_in[12];
  const float* Alog = (const float*)d_in[13];
  const float* Dp   = (const float*)d_in[14];
  const float* outW = (const float*)d_in[15];
  float* out = (float*)d_out;
  float* ws = (float*)d_ws;

  float* z   = ws+OFF_Z;
  float* zg  = ws+OFF_ZG;
  float* xsr = ws+OFF_XSR;
  float* wot = ws+OFF_XSR;   // wotv hosted in XSR head; xsr dead after k4b
  float* WcT = ws+OFF_WC;
  float* yr  = ws+OFF_YR;
  float* wti = ws+OFF_YR;    // WTiv hosted in YR head; dead before k5 writes yr
  float* dxp = ws+OFF_DPX;
  float* bcp = ws+OFF_BC;

  k0_t     <<<64,256,0,stream>>>(inW, wti);
  k2_fused <<<608,1024,0,stream>>>(zseq,aux,auxW,auxb,rmsw,wti,xpW,dtW,z,xsr,zg,WcT);
  k4b_xproj<<<512,768,0,stream>>>(xsr,convW,convb,WcT,dtb,dxp,bcp);
  k5_scan  <<<528,512,0,stream>>>(dxp,bcp,Alog,yr,outW,wot);
  k6_out   <<<512,1024,0,stream>>>(yr,dxp,zg,Dp,wot,z,lnw,lnb,out);
}